// Round 1
// 486.707 us; speedup vs baseline: 1.1457x; 1.1457x over previous
//
#include <hip/hip_runtime.h>

#define NN 100000
#define EE 1600000
#define TOT (EE + NN)
#define NEG 0.2f
#define NB 256                      // dst buckets (one fine-block each)
#define CH 391                      // nodes per bucket = ceil(NN/NB)
#define TILE 4096                   // edges per bin block
#define NTILES ((EE + TILE - 1) / TILE)   // 391
#define GEMM_BLKS ((NN + 63) / 64)  // 1563

typedef unsigned int uint;
typedef unsigned short ushort;

__device__ inline ushort f2bf(float f) {            // RNE f32 -> bf16
    uint u = __float_as_uint(f);
    return (ushort)((u + 0x7fff + ((u >> 16) & 1)) >> 16);
}

__device__ inline int imin(int a, int b) { return a < b ? a : b; }

// ---------------- bucket count ----------------
// LDS histogram per block -> 256 global atomics per block (vs 1.6M in old k_hist)

__launch_bounds__(256) __global__
void k_bcount(const int* __restrict__ dst, int* __restrict__ bcnt) {
    __shared__ int h[NB];
    int t = threadIdx.x;
    h[t] = 0;
    __syncthreads();
    int base = blockIdx.x * TILE;
#pragma unroll
    for (int r = 0; r < 16; ++r) {
        int e = base + r * 256 + t;
        if (e < EE) atomicAdd(&h[dst[e] / CH], 1);
    }
    __syncthreads();
    if (h[t]) atomicAdd(&bcnt[t], h[t]);
}

// ---------------- bucket prefix (1 block) ----------------
// boff: exclusive prefix in edge space (binned array layout), boff[NB] = EE
// bcsr: exclusive prefix in csr space (counts + 1 self-loop per node)
// bfill: running append cursor per bucket, initialized to boff

__launch_bounds__(NB) __global__
void k_bprefix(const int* __restrict__ bcnt, int* __restrict__ boff,
               int* __restrict__ bcsr, int* __restrict__ bfill) {
    __shared__ int s1[NB], s2[NB];
    int t = threadIdx.x;
    int c = bcnt[t];
    int nb0 = t * CH;
    int nib = imin(nb0 + CH, NN) - nb0;     // nodes in this bucket
    s1[t] = c; s2[t] = c + nib;
    __syncthreads();
    for (int off = 1; off < NB; off <<= 1) {
        int a = (t >= off) ? s1[t - off] : 0;
        int b = (t >= off) ? s2[t - off] : 0;
        __syncthreads();
        s1[t] += a; s2[t] += b;
        __syncthreads();
    }
    int ex = s1[t] - c;
    boff[t] = ex;
    bfill[t] = ex;
    bcsr[t] = s2[t] - (c + nib);
    if (t == NB - 1) boff[NB] = EE;
}

// ---------------- bin pass: LDS multi-split, coalesced global writes --------
// record: lo = src | (local_dst << 17)   (src < 2^17, local_dst < 391 < 2^9)
//         hi = bits(edge_weight)

__launch_bounds__(256) __global__
void k_bin(const int* __restrict__ src, const int* __restrict__ dst,
           const float* __restrict__ ew, int* __restrict__ bfill,
           long long* __restrict__ binned) {
    __shared__ long long recs[TILE];   // 32 KB, bucket-ordered staging
    __shared__ ushort    bkt[TILE];    // 8 KB
    __shared__ int hist[NB], eoff[NB], gbase[NB];
    int t = threadIdx.x;
    hist[t] = 0;
    __syncthreads();
    int base = blockIdx.x * TILE;
    int cnt = imin(TILE, EE - base);
    long long rec[16]; int binfo[16];
#pragma unroll
    for (int r = 0; r < 16; ++r) {
        int i = r * 256 + t;
        if (i < cnt) {
            int e = base + i;
            int s = src[e], d = dst[e];
            float w = ew[e];
            int b = d / CH;
            int ldst = d - b * CH;
            int rk = atomicAdd(&hist[b], 1);          // LDS atomic = within-tile rank
            rec[r] = (long long)(uint)(s | (ldst << 17)) |
                     ((long long)__float_as_uint(w) << 32);
            binfo[r] = b | (rk << 8);
        }
    }
    __syncthreads();
    int c = hist[t];
    eoff[t] = c;
    __syncthreads();
    for (int off = 1; off < NB; off <<= 1) {          // inclusive scan
        int a = (t >= off) ? eoff[t - off] : 0;
        __syncthreads();
        eoff[t] += a;
        __syncthreads();
    }
    int ex = eoff[t] - c;                             // own exclusive offset
    gbase[t] = atomicAdd(&bfill[t], c);               // reserve contiguous chunk
    eoff[t] = ex;                                     // thread-local rewrite, then barrier
    __syncthreads();
#pragma unroll
    for (int r = 0; r < 16; ++r) {                    // stage bucket-ordered in LDS
        int i = r * 256 + t;
        if (i < cnt) {
            int b = binfo[r] & 255, rk = binfo[r] >> 8;
            int slot = eoff[b] + rk;
            recs[slot] = rec[r];
            bkt[slot] = (ushort)b;
        }
    }
    __syncthreads();
#pragma unroll
    for (int r = 0; r < 16; ++r) {                    // coalesced runs (~128B/bucket)
        int i = r * 256 + t;
        if (i < cnt) {
            int b = bkt[i];
            binned[gbase[b] + (i - eoff[b])] = recs[i];
        }
    }
}

// ---------------- gemm1 body (xp = x @ Wg, bf16 out + logit epilogue) -------

__device__ __forceinline__ void gemm1_body(
    int bid, const float* __restrict__ A, const float* __restrict__ W,
    ushort* __restrict__ C16, const float* __restrict__ att_s,
    const float* __restrict__ att_d, float* __restrict__ a_s,
    float* __restrict__ a_d) {
    int lane = threadIdx.x & 63;
    int cg = __builtin_amdgcn_readfirstlane(threadIdx.x >> 6);  // 0..3
    int row = bid * 64 + lane;
    bool valid = row < NN;
    if (!valid) row = NN - 1;
    const float* __restrict__ a = A + (size_t)row * 128;
    const float* __restrict__ w = W + cg * 32;
    float acc[32];
#pragma unroll
    for (int c = 0; c < 32; ++c) acc[c] = 0.f;
    float4 xv = *(const float4*)(a);
    for (int k = 0; k < 128; k += 4) {
        float4 nx = xv;
        if (k < 124) nx = *(const float4*)(a + k + 4);   // 1-ahead prefetch
        float xs[4] = {xv.x, xv.y, xv.z, xv.w};
#pragma unroll
        for (int kk = 0; kk < 4; ++kk) {
            const float* wr = w + (k + kk) * 128;
            float xk = xs[kk];
#pragma unroll
            for (int c = 0; c < 32; ++c) acc[c] = fmaf(xk, wr[c], acc[c]);
        }
        xv = nx;
    }
    if (valid) {
        ushort* o = C16 + (size_t)row * 128 + cg * 32;
#pragma unroll
        for (int c = 0; c < 32; c += 8) {
            uint4 p;
            p.x = (uint)f2bf(acc[c+0]) | ((uint)f2bf(acc[c+1]) << 16);
            p.y = (uint)f2bf(acc[c+2]) | ((uint)f2bf(acc[c+3]) << 16);
            p.z = (uint)f2bf(acc[c+4]) | ((uint)f2bf(acc[c+5]) << 16);
            p.w = (uint)f2bf(acc[c+6]) | ((uint)f2bf(acc[c+7]) << 16);
            *(uint4*)(o + c) = p;
        }
        const float* as = att_s + cg * 32;
        const float* ad = att_d + cg * 32;
        float s0 = 0.f, s1 = 0.f;
#pragma unroll
        for (int c = 0; c < 32; ++c) {
            s0 = fmaf(acc[c], as[c], s0);
            s1 = fmaf(acc[c], ad[c], s1);
        }
        a_s[row * 4 + cg] = s0;
        a_d[row * 4 + cg] = s1;
    }
}

// ---------------- fused: fine scatter (L2-resident per bucket) + gemm1 ------
// Fine block b owns nodes [b*CH, b*CH+nnode) and csr window bcsr[b]..+(cnt+nnode):
// per-node counts + scan in LDS produce row_off directly (replaces hist+3 scans);
// the scatter stays inside a ~55 KB window -> lines fill completely in L2.

__launch_bounds__(256) __global__
void k_fine_gemm(const long long* __restrict__ binned, const int* __restrict__ boff,
                 const int* __restrict__ bcsr, int* __restrict__ row_off,
                 long long* __restrict__ csr,
                 const float* __restrict__ A, const float* __restrict__ W,
                 ushort* __restrict__ C16, const float* __restrict__ att_s,
                 const float* __restrict__ att_d, float* __restrict__ a_s,
                 float* __restrict__ a_d) {
    if (blockIdx.x >= NB) {
        gemm1_body(blockIdx.x - NB, A, W, C16, att_s, att_d, a_s, a_d);
        return;
    }
    __shared__ int hist[CH];
    __shared__ int excl[CH];
    __shared__ int sc[512];
    int t = threadIdx.x;
    int b = blockIdx.x;
    int e0 = boff[b], e1 = boff[b + 1];
    int nb0 = b * CH;
    int nnode = imin(CH, NN - nb0);
    const int2* __restrict__ bn = (const int2*)binned;
    hist[t] = 0;
    if (t + 256 < CH) hist[t + 256] = 0;
    __syncthreads();
    for (int i = e0 + t; i < e1; i += 256)            // pass 1: per-node counts
        atomicAdd(&hist[bn[i].x >> 17], 1);
    __syncthreads();
    int v0 = (t < nnode) ? hist[t] + 1 : 0;           // +1 self-loop
    int v1 = (t + 256 < nnode) ? hist[t + 256] + 1 : 0;
    sc[t] = v0; sc[t + 256] = v1;
    __syncthreads();
    for (int off = 1; off < 512; off <<= 1) {         // Hillis-Steele, 2 elems/thread
        int a0 = (t >= off) ? sc[t - off] : 0;
        int a1 = (t + 256 >= off) ? sc[t + 256 - off] : 0;
        __syncthreads();
        sc[t] += a0; sc[t + 256] += a1;
        __syncthreads();
    }
    int csr0 = bcsr[b];
    if (t < nnode) {
        excl[t] = csr0 + sc[t] - v0;
        row_off[nb0 + t] = excl[t];
    }
    if (t + 256 < nnode) {
        excl[t + 256] = csr0 + sc[t + 256] - v1;
        row_off[nb0 + t + 256] = excl[t + 256];
    }
    if (b == 0 && t == 0) row_off[NN] = TOT;
    hist[t] = 0;                                      // reset -> rank counters
    if (t + 256 < CH) hist[t + 256] = 0;
    __syncthreads();
    for (int i = e0 + t; i < e1; i += 256) {          // pass 2: L2-window scatter
        int2 r = bn[i];
        int ld = r.x >> 17;
        int rk = atomicAdd(&hist[ld], 1);
        long long rec = (long long)(uint)(r.x & 0x1FFFF) |
                        ((long long)(uint)r.y << 32);
        csr[excl[ld] + rk] = rec;
    }
    __syncthreads();
    for (int i = t; i < nnode; i += 256) {            // self-loops at row end, w = 1
        int n = nb0 + i;
        csr[excl[i] + hist[i]] = (long long)(uint)n | (0x3F800000LL << 32);
    }
}

// ---------------- GEMM2: h16 = (ygat @ Wc) * dinv[row], bf16 out -------------

__launch_bounds__(256) __global__
void k_gemm2(const float* __restrict__ A, const float* __restrict__ W,
             ushort* __restrict__ C16, const float* __restrict__ dscale) {
    int lane = threadIdx.x & 63;
    int cg = __builtin_amdgcn_readfirstlane(threadIdx.x >> 6);
    int row = blockIdx.x * 64 + lane;
    bool valid = row < NN;
    if (!valid) row = NN - 1;
    const float* __restrict__ a = A + (size_t)row * 128;
    const float* __restrict__ w = W + cg * 32;
    float acc[32];
#pragma unroll
    for (int c = 0; c < 32; ++c) acc[c] = 0.f;
    float4 xv = *(const float4*)(a);
    for (int k = 0; k < 128; k += 4) {
        float4 nx = xv;
        if (k < 124) nx = *(const float4*)(a + k + 4);
        float xs[4] = {xv.x, xv.y, xv.z, xv.w};
#pragma unroll
        for (int kk = 0; kk < 4; ++kk) {
            const float* wr = w + (k + kk) * 128;
            float xk = xs[kk];
#pragma unroll
            for (int c = 0; c < 32; ++c) acc[c] = fmaf(xk, wr[c], acc[c]);
        }
        xv = nx;
    }
    if (valid) {
        float sc = dscale[row];                 // fold dinv[src] into the row
        ushort* o = C16 + (size_t)row * 128 + cg * 32;
#pragma unroll
        for (int c = 0; c < 32; c += 8) {
            uint4 p;
            p.x = (uint)f2bf(acc[c+0]*sc) | ((uint)f2bf(acc[c+1]*sc) << 16);
            p.y = (uint)f2bf(acc[c+2]*sc) | ((uint)f2bf(acc[c+3]*sc) << 16);
            p.z = (uint)f2bf(acc[c+4]*sc) | ((uint)f2bf(acc[c+5]*sc) << 16);
            p.w = (uint)f2bf(acc[c+6]*sc) | ((uint)f2bf(acc[c+7]*sc) << 16);
            *(uint4*)(o + c) = p;
        }
    }
}

// ---------------- GAT aggregation: single pass, wave per node ----------------

__launch_bounds__(256) __global__
void k_gat(const int* __restrict__ row_off, const int2* __restrict__ csr,
           const float* __restrict__ a_s, const float* __restrict__ a_d,
           const ushort* __restrict__ xp16,
           float* __restrict__ ygat, float* __restrict__ dinv) {
    int lane = threadIdx.x & 63;
    int node = blockIdx.x * 4 + (threadIdx.x >> 6);   // NN % 4 == 0
    int base = row_off[node], end = row_off[node + 1];
    int grp = lane >> 4, sl = lane & 15, h2 = sl >> 2;
    float adh = a_d[node * 4 + h2];
    float acc[8];
#pragma unroll
    for (int j = 0; j < 8; ++j) acc[j] = 0.f;
    float den = 0.f, wsum = 0.f;
    int na = end - 1;
    int i0 = base + grp;
    int2 eA = csr[imin(i0, na)];
    int2 eB = csr[imin(i0 + 4, na)];
    for (int i = i0; i < end; i += 8) {
        int2 eA2 = csr[imin(i + 8,  na)];           // prefetch next trip
        int2 eB2 = csr[imin(i + 12, na)];
        uint4 qA = *(const uint4*)(xp16 + (size_t)eA.x * 128 + sl * 8);
        uint4 qB = *(const uint4*)(xp16 + (size_t)eB.x * 128 + sl * 8);
        float alA = a_s[eA.x * 4 + h2] + adh;
        alA = alA > 0.f ? alA : NEG * alA;
        float awA = __expf(alA);
        float awB = 0.f, wB = 0.f;
        if (i + 4 < end) {
            float alB = a_s[eB.x * 4 + h2] + adh;
            alB = alB > 0.f ? alB : NEG * alB;
            awB = __expf(alB);
            wB = __int_as_float(eB.y);
        }
        den  += awA + awB;
        wsum += __int_as_float(eA.y) + wB;
        acc[0] = fmaf(awA, __uint_as_float(qA.x << 16),         fmaf(awB, __uint_as_float(qB.x << 16),         acc[0]));
        acc[1] = fmaf(awA, __uint_as_float(qA.x & 0xffff0000u), fmaf(awB, __uint_as_float(qB.x & 0xffff0000u), acc[1]));
        acc[2] = fmaf(awA, __uint_as_float(qA.y << 16),         fmaf(awB, __uint_as_float(qB.y << 16),         acc[2]));
        acc[3] = fmaf(awA, __uint_as_float(qA.y & 0xffff0000u), fmaf(awB, __uint_as_float(qB.y & 0xffff0000u), acc[3]));
        acc[4] = fmaf(awA, __uint_as_float(qA.z << 16),         fmaf(awB, __uint_as_float(qB.z << 16),         acc[4]));
        acc[5] = fmaf(awA, __uint_as_float(qA.z & 0xffff0000u), fmaf(awB, __uint_as_float(qB.z & 0xffff0000u), acc[5]));
        acc[6] = fmaf(awA, __uint_as_float(qA.w << 16),         fmaf(awB, __uint_as_float(qB.w << 16),         acc[6]));
        acc[7] = fmaf(awA, __uint_as_float(qA.w & 0xffff0000u), fmaf(awB, __uint_as_float(qB.w & 0xffff0000u), acc[7]));
        eA = eA2; eB = eB2;
    }
#pragma unroll
    for (int j = 0; j < 8; ++j) {
        acc[j] += __shfl_xor(acc[j], 16);
        acc[j] += __shfl_xor(acc[j], 32);
    }
    den  += __shfl_xor(den, 16);   den  += __shfl_xor(den, 32);
    wsum += __shfl_xor(wsum, 16);  wsum += __shfl_xor(wsum, 32);
    if (grp == 0) {
        float il = 1.f / den;
        float* o = ygat + (size_t)node * 128 + sl * 8;
        *(float4*)(o)     = make_float4(acc[0]*il, acc[1]*il, acc[2]*il, acc[3]*il);
        *(float4*)(o + 4) = make_float4(acc[4]*il, acc[5]*il, acc[6]*il, acc[7]*il);
        if (sl == 0) dinv[node] = rsqrtf(wsum);
    }
}

// ---------------- GCN aggregation (dinv[src] pre-folded into h16) ----------

__launch_bounds__(256) __global__
void k_gcn(const int* __restrict__ row_off, const int2* __restrict__ csr,
           const float* __restrict__ dinv, const ushort* __restrict__ h16,
           float* __restrict__ out) {
    int lane = threadIdx.x & 63;
    int node = blockIdx.x * 4 + (threadIdx.x >> 6);
    int base = row_off[node], end = row_off[node + 1];
    float dn = dinv[node];
    int grp = lane >> 4, sl = lane & 15;
    float acc[8];
#pragma unroll
    for (int j = 0; j < 8; ++j) acc[j] = 0.f;
    int na = end - 1;
    int i0 = base + grp;
    int2 eA = csr[imin(i0, na)];
    int2 eB = csr[imin(i0 + 4, na)];
    for (int i = i0; i < end; i += 8) {
        int2 eA2 = csr[imin(i + 8,  na)];
        int2 eB2 = csr[imin(i + 12, na)];
        uint4 qA = *(const uint4*)(h16 + (size_t)eA.x * 128 + sl * 8);
        uint4 qB = *(const uint4*)(h16 + (size_t)eB.x * 128 + sl * 8);
        float cA = __int_as_float(eA.y) * dn;       // dinv[s] already in h16
        float cB = (i + 4 < end) ? __int_as_float(eB.y) * dn : 0.f;
        acc[0] = fmaf(cA, __uint_as_float(qA.x << 16),         fmaf(cB, __uint_as_float(qB.x << 16),         acc[0]));
        acc[1] = fmaf(cA, __uint_as_float(qA.x & 0xffff0000u), fmaf(cB, __uint_as_float(qB.x & 0xffff0000u), acc[1]));
        acc[2] = fmaf(cA, __uint_as_float(qA.y << 16),         fmaf(cB, __uint_as_float(qB.y << 16),         acc[2]));
        acc[3] = fmaf(cA, __uint_as_float(qA.y & 0xffff0000u), fmaf(cB, __uint_as_float(qB.y & 0xffff0000u), acc[3]));
        acc[4] = fmaf(cA, __uint_as_float(qA.z << 16),         fmaf(cB, __uint_as_float(qB.z << 16),         acc[4]));
        acc[5] = fmaf(cA, __uint_as_float(qA.z & 0xffff0000u), fmaf(cB, __uint_as_float(qB.z & 0xffff0000u), acc[5]));
        acc[6] = fmaf(cA, __uint_as_float(qA.w << 16),         fmaf(cB, __uint_as_float(qB.w << 16),         acc[6]));
        acc[7] = fmaf(cA, __uint_as_float(qA.w & 0xffff0000u), fmaf(cB, __uint_as_float(qB.w & 0xffff0000u), acc[7]));
        eA = eA2; eB = eB2;
    }
#pragma unroll
    for (int j = 0; j < 8; ++j) {
        acc[j] += __shfl_xor(acc[j], 16);
        acc[j] += __shfl_xor(acc[j], 32);
    }
    if (grp == 0) {
        float* o = out + (size_t)node * 128 + sl * 8;
        *(float4*)(o)     = make_float4(acc[0], acc[1], acc[2], acc[3]);
        *(float4*)(o + 4) = make_float4(acc[4], acc[5], acc[6], acc[7]);
    }
}

// ---------------- launch ----------------

extern "C" void kernel_launch(void* const* d_in, const int* in_sizes, int n_in,
                              void* d_out, int out_size, void* d_ws, size_t ws_size,
                              hipStream_t stream) {
    const float* x    = (const float*)d_in[0];
    const int*   ei   = (const int*)  d_in[1];   // [2,E]: src then dst
    const float* ew   = (const float*)d_in[2];
    const float* Wg   = (const float*)d_in[3];
    const float* atts = (const float*)d_in[4];
    const float* attd = (const float*)d_in[5];
    const float* Wc   = (const float*)d_in[6];
    float* out = (float*)d_out;

    float* ygat  = (float*)d_ws;             // 12.8M f32
    float* a_s   = ygat + 12800000;          // 400000
    float* a_d   = a_s + 400000;             // 400000
    float* dinvp = a_d + 400000;             // 100000
    int* row_off = (int*)(dinvp + 100000);   // 100004
    int* bcnt    = row_off + 100004;         // NB
    int* boff    = bcnt + NB;                // NB + 1
    int* bcsr    = boff + NB + 1;            // NB
    int* bfill   = bcsr + NB;                // NB
    long long* csr = (long long*)(bfill + NB + 1);  // pad -> 8B aligned; 1.7M x 8B
    ushort* xp16 = (ushort*)(csr + 1700000);        // 12.8M bf16
    ushort* h16  = xp16 + 12800000;                 // 12.8M bf16
    long long* binned = (long long*)h16;    // alias: binned dead before gemm2 writes h16

    const int* srcv = ei;
    const int* dstv = ei + EE;

    hipMemsetAsync(bcnt, 0, NB * sizeof(int), stream);
    k_bcount <<<NTILES, 256, 0, stream>>>(dstv, bcnt);
    k_bprefix<<<1, NB, 0, stream>>>(bcnt, boff, bcsr, bfill);
    k_bin    <<<NTILES, 256, 0, stream>>>(srcv, dstv, ew, bfill, binned);
    k_fine_gemm<<<NB + GEMM_BLKS, 256, 0, stream>>>(
        binned, boff, bcsr, row_off, csr,
        x, Wg, xp16, atts, attd, a_s, a_d);
    k_gat  <<<NN / 4, 256, 0, stream>>>(row_off, (const int2*)csr, a_s, a_d, xp16,
                                        ygat, dinvp);
    k_gemm2<<<GEMM_BLKS, 256, 0, stream>>>(ygat, Wc, h16, dinvp);
    k_gcn  <<<NN / 4, 256, 0, stream>>>(row_off, (const int2*)csr, dinvp, h16, out);
}

// Round 2
// 472.561 us; speedup vs baseline: 1.1800x; 1.0299x over previous
//
#include <hip/hip_runtime.h>

#define NN 100000
#define EE 1600000
#define TOT (EE + NN)
#define NEG 0.2f
#define NB 256                      // dst buckets (one fine-block each)
#define CH 391                      // nodes per bucket = ceil(NN/NB)
#define TILE 4096                   // edges per bin block
#define NTILES ((EE + TILE - 1) / TILE)   // 391
#define GEMM_BLKS ((NN + 63) / 64)  // 1563
#define LDA 132                     // LDS row stride (floats): 16B-aligned, conflict-free

typedef unsigned int uint;
typedef unsigned short ushort;

__device__ inline ushort f2bf(float f) {            // RNE f32 -> bf16
    uint u = __float_as_uint(f);
    return (ushort)((u + 0x7fff + ((u >> 16) & 1)) >> 16);
}

__device__ inline int imin(int a, int b) { return a < b ? a : b; }

// ---------------- bucket count ----------------

__launch_bounds__(256) __global__
void k_bcount(const int* __restrict__ dst, int* __restrict__ bcnt) {
    __shared__ int h[NB];
    int t = threadIdx.x;
    h[t] = 0;
    __syncthreads();
    int base = blockIdx.x * TILE;
#pragma unroll
    for (int r = 0; r < 16; ++r) {
        int e = base + r * 256 + t;
        if (e < EE) atomicAdd(&h[dst[e] / CH], 1);
    }
    __syncthreads();
    if (h[t]) atomicAdd(&bcnt[t], h[t]);
}

// ---------------- bucket prefix (1 block) ----------------

__launch_bounds__(NB) __global__
void k_bprefix(const int* __restrict__ bcnt, int* __restrict__ boff,
               int* __restrict__ bcsr, int* __restrict__ bfill) {
    __shared__ int s1[NB], s2[NB];
    int t = threadIdx.x;
    int c = bcnt[t];
    int nb0 = t * CH;
    int nib = imin(nb0 + CH, NN) - nb0;     // nodes in this bucket
    s1[t] = c; s2[t] = c + nib;
    __syncthreads();
    for (int off = 1; off < NB; off <<= 1) {
        int a = (t >= off) ? s1[t - off] : 0;
        int b = (t >= off) ? s2[t - off] : 0;
        __syncthreads();
        s1[t] += a; s2[t] += b;
        __syncthreads();
    }
    int ex = s1[t] - c;
    boff[t] = ex;
    bfill[t] = ex;
    bcsr[t] = s2[t] - (c + nib);
    if (t == NB - 1) boff[NB] = EE;
}

// ---------------- bin pass: LDS multi-split, coalesced global writes --------

__launch_bounds__(256) __global__
void k_bin(const int* __restrict__ src, const int* __restrict__ dst,
           const float* __restrict__ ew, int* __restrict__ bfill,
           long long* __restrict__ binned) {
    __shared__ long long recs[TILE];   // 32 KB, bucket-ordered staging
    __shared__ ushort    bkt[TILE];    // 8 KB
    __shared__ int hist[NB], eoff[NB], gbase[NB];
    int t = threadIdx.x;
    hist[t] = 0;
    __syncthreads();
    int base = blockIdx.x * TILE;
    int cnt = imin(TILE, EE - base);
    long long rec[16]; int binfo[16];
#pragma unroll
    for (int r = 0; r < 16; ++r) {
        int i = r * 256 + t;
        if (i < cnt) {
            int e = base + i;
            int s = src[e], d = dst[e];
            float w = ew[e];
            int b = d / CH;
            int ldst = d - b * CH;
            int rk = atomicAdd(&hist[b], 1);          // LDS atomic = within-tile rank
            rec[r] = (long long)(uint)(s | (ldst << 17)) |
                     ((long long)__float_as_uint(w) << 32);
            binfo[r] = b | (rk << 8);
        }
    }
    __syncthreads();
    int c = hist[t];
    eoff[t] = c;
    __syncthreads();
    for (int off = 1; off < NB; off <<= 1) {          // inclusive scan
        int a = (t >= off) ? eoff[t - off] : 0;
        __syncthreads();
        eoff[t] += a;
        __syncthreads();
    }
    int ex = eoff[t] - c;                             // own exclusive offset
    gbase[t] = atomicAdd(&bfill[t], c);               // reserve contiguous chunk
    eoff[t] = ex;
    __syncthreads();
#pragma unroll
    for (int r = 0; r < 16; ++r) {                    // stage bucket-ordered in LDS
        int i = r * 256 + t;
        if (i < cnt) {
            int b = binfo[r] & 255, rk = binfo[r] >> 8;
            int slot = eoff[b] + rk;
            recs[slot] = rec[r];
            bkt[slot] = (ushort)b;
        }
    }
    __syncthreads();
#pragma unroll
    for (int r = 0; r < 16; ++r) {                    // coalesced runs (~128B/bucket)
        int i = r * 256 + t;
        if (i < cnt) {
            int b = bkt[i];
            binned[gbase[b] + (i - eoff[b])] = recs[i];
        }
    }
}

// ---------------- gemm1 body (xp = x @ Wg, bf16 out + logit epilogue) -------

__device__ __forceinline__ void gemm1_body(
    int bid, const float* __restrict__ A, const float* __restrict__ W,
    ushort* __restrict__ C16, const float* __restrict__ att_s,
    const float* __restrict__ att_d, float* __restrict__ a_s,
    float* __restrict__ a_d) {
    int lane = threadIdx.x & 63;
    int cg = __builtin_amdgcn_readfirstlane(threadIdx.x >> 6);  // 0..3
    int row = bid * 64 + lane;
    bool valid = row < NN;
    if (!valid) row = NN - 1;
    const float* __restrict__ a = A + (size_t)row * 128;
    const float* __restrict__ w = W + cg * 32;
    float acc[32];
#pragma unroll
    for (int c = 0; c < 32; ++c) acc[c] = 0.f;
    float4 xv = *(const float4*)(a);
    for (int k = 0; k < 128; k += 4) {
        float4 nx = xv;
        if (k < 124) nx = *(const float4*)(a + k + 4);   // 1-ahead prefetch
        float xs[4] = {xv.x, xv.y, xv.z, xv.w};
#pragma unroll
        for (int kk = 0; kk < 4; ++kk) {
            const float* wr = w + (k + kk) * 128;
            float xk = xs[kk];
#pragma unroll
            for (int c = 0; c < 32; ++c) acc[c] = fmaf(xk, wr[c], acc[c]);
        }
        xv = nx;
    }
    if (valid) {
        ushort* o = C16 + (size_t)row * 128 + cg * 32;
#pragma unroll
        for (int c = 0; c < 32; c += 8) {
            uint4 p;
            p.x = (uint)f2bf(acc[c+0]) | ((uint)f2bf(acc[c+1]) << 16);
            p.y = (uint)f2bf(acc[c+2]) | ((uint)f2bf(acc[c+3]) << 16);
            p.z = (uint)f2bf(acc[c+4]) | ((uint)f2bf(acc[c+5]) << 16);
            p.w = (uint)f2bf(acc[c+6]) | ((uint)f2bf(acc[c+7]) << 16);
            *(uint4*)(o + c) = p;
        }
        const float* as = att_s + cg * 32;
        const float* ad = att_d + cg * 32;
        float s0 = 0.f, s1 = 0.f;
#pragma unroll
        for (int c = 0; c < 32; ++c) {
            s0 = fmaf(acc[c], as[c], s0);
            s1 = fmaf(acc[c], ad[c], s1);
        }
        a_s[row * 4 + cg] = s0;
        a_d[row * 4 + cg] = s1;
    }
}

// ---------------- fused: fine scatter (L2-resident per bucket) + gemm1 ------

__launch_bounds__(256) __global__
void k_fine_gemm(const long long* __restrict__ binned, const int* __restrict__ boff,
                 const int* __restrict__ bcsr, int* __restrict__ row_off,
                 long long* __restrict__ csr,
                 const float* __restrict__ A, const float* __restrict__ W,
                 ushort* __restrict__ C16, const float* __restrict__ att_s,
                 const float* __restrict__ att_d, float* __restrict__ a_s,
                 float* __restrict__ a_d) {
    if (blockIdx.x >= NB) {
        gemm1_body(blockIdx.x - NB, A, W, C16, att_s, att_d, a_s, a_d);
        return;
    }
    __shared__ int hist[CH];
    __shared__ int excl[CH];
    __shared__ int sc[512];
    int t = threadIdx.x;
    int b = blockIdx.x;
    int e0 = boff[b], e1 = boff[b + 1];
    int nb0 = b * CH;
    int nnode = imin(CH, NN - nb0);
    const int2* __restrict__ bn = (const int2*)binned;
    hist[t] = 0;
    if (t + 256 < CH) hist[t + 256] = 0;
    __syncthreads();
    for (int i = e0 + t; i < e1; i += 256)            // pass 1: per-node counts
        atomicAdd(&hist[bn[i].x >> 17], 1);
    __syncthreads();
    int v0 = (t < nnode) ? hist[t] + 1 : 0;           // +1 self-loop
    int v1 = (t + 256 < nnode) ? hist[t + 256] + 1 : 0;
    sc[t] = v0; sc[t + 256] = v1;
    __syncthreads();
    for (int off = 1; off < 512; off <<= 1) {         // Hillis-Steele, 2 elems/thread
        int a0 = (t >= off) ? sc[t - off] : 0;
        int a1 = (t + 256 >= off) ? sc[t + 256 - off] : 0;
        __syncthreads();
        sc[t] += a0; sc[t + 256] += a1;
        __syncthreads();
    }
    int csr0 = bcsr[b];
    if (t < nnode) {
        excl[t] = csr0 + sc[t] - v0;
        row_off[nb0 + t] = excl[t];
    }
    if (t + 256 < nnode) {
        excl[t + 256] = csr0 + sc[t + 256] - v1;
        row_off[nb0 + t + 256] = excl[t + 256];
    }
    if (b == 0 && t == 0) row_off[NN] = TOT;
    hist[t] = 0;                                      // reset -> rank counters
    if (t + 256 < CH) hist[t + 256] = 0;
    __syncthreads();
    for (int i = e0 + t; i < e1; i += 256) {          // pass 2: L2-window scatter
        int2 r = bn[i];
        int ld = r.x >> 17;
        int rk = atomicAdd(&hist[ld], 1);
        long long rec = (long long)(uint)(r.x & 0x1FFFF) |
                        ((long long)(uint)r.y << 32);
        csr[excl[ld] + rk] = rec;
    }
    __syncthreads();
    for (int i = t; i < nnode; i += 256) {            // self-loops at row end, w = 1
        int n = nb0 + i;
        csr[excl[i] + hist[i]] = (long long)(uint)n | (0x3F800000LL << 32);
    }
}

// ---------------- fused GAT aggregation + GEMM2 ------------------------------
// Block owns 64 nodes. Phase 1: 16 rounds x (4 waves x 1 node) of the single-
// pass online aggregation, rows parked in a 33KB LDS tile (stride 132 floats:
// 16B-aligned, conflict-free for lane=row ds_read_b128). Phase 2: the gemm2
// body (h16 = (ygat @ Wc) * dinv) reads A from LDS. Eliminates the 102 MB
// ygat HBM round trip + one dispatch; numerics bit-identical.

__launch_bounds__(256) __global__
void k_gat_g2(const int* __restrict__ row_off, const int2* __restrict__ csr,
              const float* __restrict__ a_s, const float* __restrict__ a_d,
              const ushort* __restrict__ xp16, const float* __restrict__ W,
              ushort* __restrict__ h16, float* __restrict__ dinv) {
    __shared__ float As[64 * LDA];
    __shared__ float sdinv[64];
    int lane = threadIdx.x & 63;
    int wv = threadIdx.x >> 6;
    int grp = lane >> 4, sl = lane & 15, h2 = sl >> 2;
    int nbase = blockIdx.x * 64;

    for (int rnd = 0; rnd < 16; ++rnd) {
        int r = (rnd << 2) | wv;            // row in block
        int node = nbase + r;
        if (node < NN) {
            int base = row_off[node], end = row_off[node + 1];
            float adh = a_d[node * 4 + h2];
            float acc[8];
#pragma unroll
            for (int j = 0; j < 8; ++j) acc[j] = 0.f;
            float den = 0.f, wsum = 0.f;
            int na = end - 1;
            int i0 = base + grp;
            int2 eA = csr[imin(i0, na)];
            int2 eB = csr[imin(i0 + 4, na)];
            for (int i = i0; i < end; i += 8) {
                int2 eA2 = csr[imin(i + 8,  na)];       // prefetch next trip
                int2 eB2 = csr[imin(i + 12, na)];
                uint4 qA = *(const uint4*)(xp16 + (size_t)eA.x * 128 + sl * 8);
                uint4 qB = *(const uint4*)(xp16 + (size_t)eB.x * 128 + sl * 8);
                float alA = a_s[eA.x * 4 + h2] + adh;
                alA = alA > 0.f ? alA : NEG * alA;
                float awA = __expf(alA);
                float awB = 0.f, wB = 0.f;
                if (i + 4 < end) {
                    float alB = a_s[eB.x * 4 + h2] + adh;
                    alB = alB > 0.f ? alB : NEG * alB;
                    awB = __expf(alB);
                    wB = __int_as_float(eB.y);
                }
                den  += awA + awB;
                wsum += __int_as_float(eA.y) + wB;
                acc[0] = fmaf(awA, __uint_as_float(qA.x << 16),         fmaf(awB, __uint_as_float(qB.x << 16),         acc[0]));
                acc[1] = fmaf(awA, __uint_as_float(qA.x & 0xffff0000u), fmaf(awB, __uint_as_float(qB.x & 0xffff0000u), acc[1]));
                acc[2] = fmaf(awA, __uint_as_float(qA.y << 16),         fmaf(awB, __uint_as_float(qB.y << 16),         acc[2]));
                acc[3] = fmaf(awA, __uint_as_float(qA.y & 0xffff0000u), fmaf(awB, __uint_as_float(qB.y & 0xffff0000u), acc[3]));
                acc[4] = fmaf(awA, __uint_as_float(qA.z << 16),         fmaf(awB, __uint_as_float(qB.z << 16),         acc[4]));
                acc[5] = fmaf(awA, __uint_as_float(qA.z & 0xffff0000u), fmaf(awB, __uint_as_float(qB.z & 0xffff0000u), acc[5]));
                acc[6] = fmaf(awA, __uint_as_float(qA.w << 16),         fmaf(awB, __uint_as_float(qB.w << 16),         acc[6]));
                acc[7] = fmaf(awA, __uint_as_float(qA.w & 0xffff0000u), fmaf(awB, __uint_as_float(qB.w & 0xffff0000u), acc[7]));
                eA = eA2; eB = eB2;
            }
#pragma unroll
            for (int j = 0; j < 8; ++j) {
                acc[j] += __shfl_xor(acc[j], 16);
                acc[j] += __shfl_xor(acc[j], 32);
            }
            den  += __shfl_xor(den, 16);   den  += __shfl_xor(den, 32);
            wsum += __shfl_xor(wsum, 16);  wsum += __shfl_xor(wsum, 32);
            if (grp == 0) {
                float il = 1.f / den;
                float* o = &As[r * LDA + sl * 8];
                *(float4*)(o)     = make_float4(acc[0]*il, acc[1]*il, acc[2]*il, acc[3]*il);
                *(float4*)(o + 4) = make_float4(acc[4]*il, acc[5]*il, acc[6]*il, acc[7]*il);
                if (sl == 0) {
                    float dv = rsqrtf(wsum);
                    sdinv[r] = dv;
                    dinv[node] = dv;        // k_gcn needs the dst-side factor
                }
            }
        } else if (grp == 0) {              // tail block: zero-fill invalid rows
            float* o = &As[r * LDA + sl * 8];
            *(float4*)(o)     = make_float4(0.f, 0.f, 0.f, 0.f);
            *(float4*)(o + 4) = make_float4(0.f, 0.f, 0.f, 0.f);
            if (sl == 0) sdinv[r] = 0.f;
        }
    }
    __syncthreads();

    // ---- phase 2: gemm2 body, A from LDS (row = lane) ----
    int cg = __builtin_amdgcn_readfirstlane(wv);
    int row = nbase + lane;
    bool valid = row < NN;
    const float* __restrict__ w = W + cg * 32;
    const float* __restrict__ a = &As[lane * LDA];
    float acc[32];
#pragma unroll
    for (int c = 0; c < 32; ++c) acc[c] = 0.f;
    for (int k = 0; k < 128; k += 4) {
        float4 xv = *(const float4*)(a + k);
        float xs[4] = {xv.x, xv.y, xv.z, xv.w};
#pragma unroll
        for (int kk = 0; kk < 4; ++kk) {
            const float* wr = w + (k + kk) * 128;
            float xk = xs[kk];
#pragma unroll
            for (int c = 0; c < 32; ++c) acc[c] = fmaf(xk, wr[c], acc[c]);
        }
    }
    if (valid) {
        float sc = sdinv[lane];                 // fold dinv[src] into the row
        ushort* o = h16 + (size_t)row * 128 + cg * 32;
#pragma unroll
        for (int c = 0; c < 32; c += 8) {
            uint4 p;
            p.x = (uint)f2bf(acc[c+0]*sc) | ((uint)f2bf(acc[c+1]*sc) << 16);
            p.y = (uint)f2bf(acc[c+2]*sc) | ((uint)f2bf(acc[c+3]*sc) << 16);
            p.z = (uint)f2bf(acc[c+4]*sc) | ((uint)f2bf(acc[c+5]*sc) << 16);
            p.w = (uint)f2bf(acc[c+6]*sc) | ((uint)f2bf(acc[c+7]*sc) << 16);
            *(uint4*)(o + c) = p;
        }
    }
}

// ---------------- GCN aggregation (dinv[src] pre-folded into h16) ----------

__launch_bounds__(256) __global__
void k_gcn(const int* __restrict__ row_off, const int2* __restrict__ csr,
           const float* __restrict__ dinv, const ushort* __restrict__ h16,
           float* __restrict__ out) {
    int lane = threadIdx.x & 63;
    int node = blockIdx.x * 4 + (threadIdx.x >> 6);
    int base = row_off[node], end = row_off[node + 1];
    float dn = dinv[node];
    int grp = lane >> 4, sl = lane & 15;
    float acc[8];
#pragma unroll
    for (int j = 0; j < 8; ++j) acc[j] = 0.f;
    int na = end - 1;
    int i0 = base + grp;
    int2 eA = csr[imin(i0, na)];
    int2 eB = csr[imin(i0 + 4, na)];
    for (int i = i0; i < end; i += 8) {
        int2 eA2 = csr[imin(i + 8,  na)];
        int2 eB2 = csr[imin(i + 12, na)];
        uint4 qA = *(const uint4*)(h16 + (size_t)eA.x * 128 + sl * 8);
        uint4 qB = *(const uint4*)(h16 + (size_t)eB.x * 128 + sl * 8);
        float cA = __int_as_float(eA.y) * dn;       // dinv[s] already in h16
        float cB = (i + 4 < end) ? __int_as_float(eB.y) * dn : 0.f;
        acc[0] = fmaf(cA, __uint_as_float(qA.x << 16),         fmaf(cB, __uint_as_float(qB.x << 16),         acc[0]));
        acc[1] = fmaf(cA, __uint_as_float(qA.x & 0xffff0000u), fmaf(cB, __uint_as_float(qB.x & 0xffff0000u), acc[1]));
        acc[2] = fmaf(cA, __uint_as_float(qA.y << 16),         fmaf(cB, __uint_as_float(qB.y << 16),         acc[2]));
        acc[3] = fmaf(cA, __uint_as_float(qA.y & 0xffff0000u), fmaf(cB, __uint_as_float(qB.y & 0xffff0000u), acc[3]));
        acc[4] = fmaf(cA, __uint_as_float(qA.z << 16),         fmaf(cB, __uint_as_float(qB.z << 16),         acc[4]));
        acc[5] = fmaf(cA, __uint_as_float(qA.z & 0xffff0000u), fmaf(cB, __uint_as_float(qB.z & 0xffff0000u), acc[5]));
        acc[6] = fmaf(cA, __uint_as_float(qA.w << 16),         fmaf(cB, __uint_as_float(qB.w << 16),         acc[6]));
        acc[7] = fmaf(cA, __uint_as_float(qA.w & 0xffff0000u), fmaf(cB, __uint_as_float(qB.w & 0xffff0000u), acc[7]));
        eA = eA2; eB = eB2;
    }
#pragma unroll
    for (int j = 0; j < 8; ++j) {
        acc[j] += __shfl_xor(acc[j], 16);
        acc[j] += __shfl_xor(acc[j], 32);
    }
    if (grp == 0) {
        float* o = out + (size_t)node * 128 + sl * 8;
        *(float4*)(o)     = make_float4(acc[0], acc[1], acc[2], acc[3]);
        *(float4*)(o + 4) = make_float4(acc[4], acc[5], acc[6], acc[7]);
    }
}

// ---------------- launch ----------------

extern "C" void kernel_launch(void* const* d_in, const int* in_sizes, int n_in,
                              void* d_out, int out_size, void* d_ws, size_t ws_size,
                              hipStream_t stream) {
    const float* x    = (const float*)d_in[0];
    const int*   ei   = (const int*)  d_in[1];   // [2,E]: src then dst
    const float* ew   = (const float*)d_in[2];
    const float* Wg   = (const float*)d_in[3];
    const float* atts = (const float*)d_in[4];
    const float* attd = (const float*)d_in[5];
    const float* Wc   = (const float*)d_in[6];
    float* out = (float*)d_out;

    float* a_s   = (float*)d_ws;             // 400000
    float* a_d   = a_s + 400000;             // 400000
    float* dinvp = a_d + 400000;             // 100000
    int* row_off = (int*)(dinvp + 100000);   // 100004
    int* bcnt    = row_off + 100004;         // NB
    int* boff    = bcnt + NB;                // NB + 1
    int* bcsr    = boff + NB + 1;            // NB
    int* bfill   = bcsr + NB;                // NB
    long long* csr = (long long*)(bfill + NB + 1);  // pad -> 8B aligned; 1.7M x 8B
    ushort* xp16 = (ushort*)(csr + 1700000);        // 12.8M bf16
    ushort* h16  = xp16 + 12800000;                 // 12.8M bf16
    long long* binned = (long long*)h16;    // alias: binned dead before h16 written

    const int* srcv = ei;
    const int* dstv = ei + EE;

    hipMemsetAsync(bcnt, 0, NB * sizeof(int), stream);
    k_bcount <<<NTILES, 256, 0, stream>>>(dstv, bcnt);
    k_bprefix<<<1, NB, 0, stream>>>(bcnt, boff, bcsr, bfill);
    k_bin    <<<NTILES, 256, 0, stream>>>(srcv, dstv, ew, bfill, binned);
    k_fine_gemm<<<NB + GEMM_BLKS, 256, 0, stream>>>(
        binned, boff, bcsr, row_off, csr,
        x, Wg, xp16, atts, attd, a_s, a_d);
    k_gat_g2<<<GEMM_BLKS, 256, 0, stream>>>(row_off, (const int2*)csr, a_s, a_d,
                                            xp16, Wc, h16, dinvp);
    k_gcn  <<<NN / 4, 256, 0, stream>>>(row_off, (const int2*)csr, dinvp, h16, out);
}

// Round 4
// 456.434 us; speedup vs baseline: 1.2217x; 1.0353x over previous
//
#include <hip/hip_runtime.h>

#define NN 100000
#define EE 1600000
#define TOT (EE + NN)
#define NEG 0.2f
#define NB 256                      // dst buckets (one fine-block each)
#define CH 391                      // nodes per bucket = ceil(NN/NB)
#define TILE 4096                   // edges per bin block
#define NTILES ((EE + TILE - 1) / TILE)   // 391
#define GEMM_BLKS ((NN + 63) / 64)  // 1563
#define LDA 132                     // LDS row stride (floats): 16B-aligned

typedef unsigned int uint;
typedef unsigned short ushort;

__device__ inline ushort f2bf(float f) {            // RNE f32 -> bf16
    uint u = __float_as_uint(f);
    return (ushort)((u + 0x7fff + ((u >> 16) & 1)) >> 16);
}

__device__ inline int imin(int a, int b) { return a < b ? a : b; }

// ---------------- bucket count ----------------

__launch_bounds__(256) __global__
void k_bcount(const int* __restrict__ dst, int* __restrict__ bcnt) {
    __shared__ int h[NB];
    int t = threadIdx.x;
    h[t] = 0;
    __syncthreads();
    int base = blockIdx.x * TILE;
#pragma unroll
    for (int r = 0; r < 16; ++r) {
        int e = base + r * 256 + t;
        if (e < EE) atomicAdd(&h[dst[e] / CH], 1);
    }
    __syncthreads();
    if (h[t]) atomicAdd(&bcnt[t], h[t]);
}

// ---------------- bucket prefix (1 block) ----------------

__launch_bounds__(NB) __global__
void k_bprefix(const int* __restrict__ bcnt, int* __restrict__ boff,
               int* __restrict__ bcsr, int* __restrict__ bfill) {
    __shared__ int s1[NB], s2[NB];
    int t = threadIdx.x;
    int c = bcnt[t];
    int nb0 = t * CH;
    int nib = imin(nb0 + CH, NN) - nb0;     // nodes in this bucket
    s1[t] = c; s2[t] = c + nib;
    __syncthreads();
    for (int off = 1; off < NB; off <<= 1) {
        int a = (t >= off) ? s1[t - off] : 0;
        int b = (t >= off) ? s2[t - off] : 0;
        __syncthreads();
        s1[t] += a; s2[t] += b;
        __syncthreads();
    }
    int ex = s1[t] - c;
    boff[t] = ex;
    bfill[t] = ex;
    bcsr[t] = s2[t] - (c + nib);
    if (t == NB - 1) boff[NB] = EE;
}

// ---------------- bin pass: LDS multi-split, coalesced global writes --------

__launch_bounds__(256) __global__
void k_bin(const int* __restrict__ src, const int* __restrict__ dst,
           const float* __restrict__ ew, int* __restrict__ bfill,
           long long* __restrict__ binned) {
    __shared__ long long recs[TILE];   // 32 KB, bucket-ordered staging
    __shared__ ushort    bkt[TILE];    // 8 KB
    __shared__ int hist[NB], eoff[NB], gbase[NB];
    int t = threadIdx.x;
    hist[t] = 0;
    __syncthreads();
    int base = blockIdx.x * TILE;
    int cnt = imin(TILE, EE - base);
    long long rec[16]; int binfo[16];
#pragma unroll
    for (int r = 0; r < 16; ++r) {
        int i = r * 256 + t;
        if (i < cnt) {
            int e = base + i;
            int s = src[e], d = dst[e];
            float w = ew[e];
            int b = d / CH;
            int ldst = d - b * CH;
            int rk = atomicAdd(&hist[b], 1);          // LDS atomic = within-tile rank
            rec[r] = (long long)(uint)(s | (ldst << 17)) |
                     ((long long)__float_as_uint(w) << 32);
            binfo[r] = b | (rk << 8);
        }
    }
    __syncthreads();
    int c = hist[t];
    eoff[t] = c;
    __syncthreads();
    for (int off = 1; off < NB; off <<= 1) {          // inclusive scan
        int a = (t >= off) ? eoff[t - off] : 0;
        __syncthreads();
        eoff[t] += a;
        __syncthreads();
    }
    int ex = eoff[t] - c;                             // own exclusive offset
    gbase[t] = atomicAdd(&bfill[t], c);               // reserve contiguous chunk
    eoff[t] = ex;
    __syncthreads();
#pragma unroll
    for (int r = 0; r < 16; ++r) {                    // stage bucket-ordered in LDS
        int i = r * 256 + t;
        if (i < cnt) {
            int b = binfo[r] & 255, rk = binfo[r] >> 8;
            int slot = eoff[b] + rk;
            recs[slot] = rec[r];
            bkt[slot] = (ushort)b;
        }
    }
    __syncthreads();
#pragma unroll
    for (int r = 0; r < 16; ++r) {                    // coalesced runs (~128B/bucket)
        int i = r * 256 + t;
        if (i < cnt) {
            int b = bkt[i];
            binned[gbase[b] + (i - eoff[b])] = recs[i];
        }
    }
}

// ---------------- gemm1 body (xp = x @ Wg, bf16 out + logit epilogue) -------

__device__ __forceinline__ void gemm1_body(
    int bid, const float* __restrict__ A, const float* __restrict__ W,
    ushort* __restrict__ C16, const float* __restrict__ att_s,
    const float* __restrict__ att_d, float* __restrict__ a_s,
    float* __restrict__ a_d) {
    int lane = threadIdx.x & 63;
    int cg = __builtin_amdgcn_readfirstlane(threadIdx.x >> 6);  // 0..3
    int row = bid * 64 + lane;
    bool valid = row < NN;
    if (!valid) row = NN - 1;
    const float* __restrict__ a = A + (size_t)row * 128;
    const float* __restrict__ w = W + cg * 32;
    float acc[32];
#pragma unroll
    for (int c = 0; c < 32; ++c) acc[c] = 0.f;
    float4 xv = *(const float4*)(a);
    for (int k = 0; k < 128; k += 4) {
        float4 nx = xv;
        if (k < 124) nx = *(const float4*)(a + k + 4);   // 1-ahead prefetch
        float xs[4] = {xv.x, xv.y, xv.z, xv.w};
#pragma unroll
        for (int kk = 0; kk < 4; ++kk) {
            const float* wr = w + (k + kk) * 128;
            float xk = xs[kk];
#pragma unroll
            for (int c = 0; c < 32; ++c) acc[c] = fmaf(xk, wr[c], acc[c]);
        }
        xv = nx;
    }
    if (valid) {
        ushort* o = C16 + (size_t)row * 128 + cg * 32;
#pragma unroll
        for (int c = 0; c < 32; c += 8) {
            uint4 p;
            p.x = (uint)f2bf(acc[c+0]) | ((uint)f2bf(acc[c+1]) << 16);
            p.y = (uint)f2bf(acc[c+2]) | ((uint)f2bf(acc[c+3]) << 16);
            p.z = (uint)f2bf(acc[c+4]) | ((uint)f2bf(acc[c+5]) << 16);
            p.w = (uint)f2bf(acc[c+6]) | ((uint)f2bf(acc[c+7]) << 16);
            *(uint4*)(o + c) = p;
        }
        const float* as = att_s + cg * 32;
        const float* ad = att_d + cg * 32;
        float s0 = 0.f, s1 = 0.f;
#pragma unroll
        for (int c = 0; c < 32; ++c) {
            s0 = fmaf(acc[c], as[c], s0);
            s1 = fmaf(acc[c], ad[c], s1);
        }
        a_s[row * 4 + cg] = s0;
        a_d[row * 4 + cg] = s1;
    }
}

// ---------------- fused: fine scatter (L2-resident per bucket) + gemm1 ------

__launch_bounds__(256) __global__
void k_fine_gemm(const long long* __restrict__ binned, const int* __restrict__ boff,
                 const int* __restrict__ bcsr, int* __restrict__ row_off,
                 long long* __restrict__ csr,
                 const float* __restrict__ A, const float* __restrict__ W,
                 ushort* __restrict__ C16, const float* __restrict__ att_s,
                 const float* __restrict__ att_d, float* __restrict__ a_s,
                 float* __restrict__ a_d) {
    if (blockIdx.x >= NB) {
        gemm1_body(blockIdx.x - NB, A, W, C16, att_s, att_d, a_s, a_d);
        return;
    }
    __shared__ int hist[CH];
    __shared__ int excl[CH];
    __shared__ int sc[512];
    int t = threadIdx.x;
    int b = blockIdx.x;
    int e0 = boff[b], e1 = boff[b + 1];
    int nb0 = b * CH;
    int nnode = imin(CH, NN - nb0);
    const int2* __restrict__ bn = (const int2*)binned;
    hist[t] = 0;
    if (t + 256 < CH) hist[t + 256] = 0;
    __syncthreads();
    for (int i = e0 + t; i < e1; i += 256)            // pass 1: per-node counts
        atomicAdd(&hist[bn[i].x >> 17], 1);
    __syncthreads();
    int v0 = (t < nnode) ? hist[t] + 1 : 0;           // +1 self-loop
    int v1 = (t + 256 < nnode) ? hist[t + 256] + 1 : 0;
    sc[t] = v0; sc[t + 256] = v1;
    __syncthreads();
    for (int off = 1; off < 512; off <<= 1) {         // Hillis-Steele, 2 elems/thread
        int a0 = (t >= off) ? sc[t - off] : 0;
        int a1 = (t + 256 >= off) ? sc[t + 256 - off] : 0;
        __syncthreads();
        sc[t] += a0; sc[t + 256] += a1;
        __syncthreads();
    }
    int csr0 = bcsr[b];
    if (t < nnode) {
        excl[t] = csr0 + sc[t] - v0;
        row_off[nb0 + t] = excl[t];
    }
    if (t + 256 < nnode) {
        excl[t + 256] = csr0 + sc[t + 256] - v1;
        row_off[nb0 + t + 256] = excl[t + 256];
    }
    if (b == 0 && t == 0) row_off[NN] = TOT;
    hist[t] = 0;                                      // reset -> rank counters
    if (t + 256 < CH) hist[t + 256] = 0;
    __syncthreads();
    for (int i = e0 + t; i < e1; i += 256) {          // pass 2: L2-window scatter
        int2 r = bn[i];
        int ld = r.x >> 17;
        int rk = atomicAdd(&hist[ld], 1);
        long long rec = (long long)(uint)(r.x & 0x1FFFF) |
                        ((long long)(uint)r.y << 32);
        csr[excl[ld] + rk] = rec;
    }
    __syncthreads();
    for (int i = t; i < nnode; i += 256) {            // self-loops at row end, w = 1
        int n = nb0 + i;
        csr[excl[i] + hist[i]] = (long long)(uint)n | (0x3F800000LL << 32);
    }
}

// ---------------- fused GAT aggregation + GEMM2 (512-thread blocks) ----------
// Round-1 fusion failed on occupancy: 34KB LDS @ 256-thread blocks -> 4 blk/CU
// = 16 waves/CU, which halved random-gather concurrency (2.05 vs 3.96 TB/s).
// Fix: 8 waves share one 64-row tile. 4 blk/CU x 8 waves = 32 waves/CU (full),
// same chip-wide LDS footprint. Phase 1: 8 rounds x 8 waves = 64 nodes, agg
// code unchanged (bit-identical). Phase 2: 64 rows x 8 col-groups of 16.

__launch_bounds__(512) __global__
void k_gat_g2(const int* __restrict__ row_off, const int2* __restrict__ csr,
              const float* __restrict__ a_s, const float* __restrict__ a_d,
              const ushort* __restrict__ xp16, const float* __restrict__ W,
              ushort* __restrict__ h16, float* __restrict__ dinv) {
    __shared__ float As[64 * LDA];
    __shared__ float sdinv[64];
    int lane = threadIdx.x & 63;
    int wv = threadIdx.x >> 6;              // 0..7
    int grp = lane >> 4, sl = lane & 15, h2 = sl >> 2;
    int nbase = blockIdx.x * 64;

    for (int rnd = 0; rnd < 8; ++rnd) {
        int r = (rnd << 3) | wv;            // row in block, 0..63
        int node = nbase + r;
        if (node < NN) {
            int base = row_off[node], end = row_off[node + 1];
            float adh = a_d[node * 4 + h2];
            float acc[8];
#pragma unroll
            for (int j = 0; j < 8; ++j) acc[j] = 0.f;
            float den = 0.f, wsum = 0.f;
            int na = end - 1;
            int i0 = base + grp;
            int2 eA = csr[imin(i0, na)];
            int2 eB = csr[imin(i0 + 4, na)];
            for (int i = i0; i < end; i += 8) {
                int2 eA2 = csr[imin(i + 8,  na)];       // prefetch next trip
                int2 eB2 = csr[imin(i + 12, na)];
                uint4 qA = *(const uint4*)(xp16 + (size_t)eA.x * 128 + sl * 8);
                uint4 qB = *(const uint4*)(xp16 + (size_t)eB.x * 128 + sl * 8);
                float alA = a_s[eA.x * 4 + h2] + adh;
                alA = alA > 0.f ? alA : NEG * alA;
                float awA = __expf(alA);
                float awB = 0.f, wB = 0.f;
                if (i + 4 < end) {
                    float alB = a_s[eB.x * 4 + h2] + adh;
                    alB = alB > 0.f ? alB : NEG * alB;
                    awB = __expf(alB);
                    wB = __int_as_float(eB.y);
                }
                den  += awA + awB;
                wsum += __int_as_float(eA.y) + wB;
                acc[0] = fmaf(awA, __uint_as_float(qA.x << 16),         fmaf(awB, __uint_as_float(qB.x << 16),         acc[0]));
                acc[1] = fmaf(awA, __uint_as_float(qA.x & 0xffff0000u), fmaf(awB, __uint_as_float(qB.x & 0xffff0000u), acc[1]));
                acc[2] = fmaf(awA, __uint_as_float(qA.y << 16),         fmaf(awB, __uint_as_float(qB.y << 16),         acc[2]));
                acc[3] = fmaf(awA, __uint_as_float(qA.y & 0xffff0000u), fmaf(awB, __uint_as_float(qB.y & 0xffff0000u), acc[3]));
                acc[4] = fmaf(awA, __uint_as_float(qA.z << 16),         fmaf(awB, __uint_as_float(qB.z << 16),         acc[4]));
                acc[5] = fmaf(awA, __uint_as_float(qA.z & 0xffff0000u), fmaf(awB, __uint_as_float(qB.z & 0xffff0000u), acc[5]));
                acc[6] = fmaf(awA, __uint_as_float(qA.w << 16),         fmaf(awB, __uint_as_float(qB.w << 16),         acc[6]));
                acc[7] = fmaf(awA, __uint_as_float(qA.w & 0xffff0000u), fmaf(awB, __uint_as_float(qB.w & 0xffff0000u), acc[7]));
                eA = eA2; eB = eB2;
            }
#pragma unroll
            for (int j = 0; j < 8; ++j) {
                acc[j] += __shfl_xor(acc[j], 16);
                acc[j] += __shfl_xor(acc[j], 32);
            }
            den  += __shfl_xor(den, 16);   den  += __shfl_xor(den, 32);
            wsum += __shfl_xor(wsum, 16);  wsum += __shfl_xor(wsum, 32);
            if (grp == 0) {
                float il = 1.f / den;
                float* o = &As[r * LDA + sl * 8];
                *(float4*)(o)     = make_float4(acc[0]*il, acc[1]*il, acc[2]*il, acc[3]*il);
                *(float4*)(o + 4) = make_float4(acc[4]*il, acc[5]*il, acc[6]*il, acc[7]*il);
                if (sl == 0) {
                    float dv = rsqrtf(wsum);
                    sdinv[r] = dv;
                    dinv[node] = dv;        // k_gcn needs the dst-side factor
                }
            }
        } else if (grp == 0) {              // tail block: zero-fill invalid rows
            float* o = &As[r * LDA + sl * 8];
            *(float4*)(o)     = make_float4(0.f, 0.f, 0.f, 0.f);
            *(float4*)(o + 4) = make_float4(0.f, 0.f, 0.f, 0.f);
            if (sl == 0) sdinv[r] = 0.f;
        }
    }
    __syncthreads();

    // ---- phase 2: gemm2 body, A from LDS (row = lane, cg = wave, 16 cols) ----
    int cg = __builtin_amdgcn_readfirstlane(wv);    // 0..7
    int row = nbase + lane;
    bool valid = row < NN;
    const float* __restrict__ w = W + cg * 16;
    const float* __restrict__ a = &As[lane * LDA];
    float acc[16];
#pragma unroll
    for (int c = 0; c < 16; ++c) acc[c] = 0.f;
    for (int k = 0; k < 128; k += 4) {
        float4 xv = *(const float4*)(a + k);
        float xs[4] = {xv.x, xv.y, xv.z, xv.w};
#pragma unroll
        for (int kk = 0; kk < 4; ++kk) {
            const float* wr = w + (k + kk) * 128;
            float xk = xs[kk];
#pragma unroll
            for (int c = 0; c < 16; ++c) acc[c] = fmaf(xk, wr[c], acc[c]);
        }
    }
    if (valid) {
        float sc = sdinv[lane];                 // fold dinv[src] into the row
        ushort* o = h16 + (size_t)row * 128 + cg * 16;
#pragma unroll
        for (int c = 0; c < 16; c += 8) {
            uint4 p;
            p.x = (uint)f2bf(acc[c+0]*sc) | ((uint)f2bf(acc[c+1]*sc) << 16);
            p.y = (uint)f2bf(acc[c+2]*sc) | ((uint)f2bf(acc[c+3]*sc) << 16);
            p.z = (uint)f2bf(acc[c+4]*sc) | ((uint)f2bf(acc[c+5]*sc) << 16);
            p.w = (uint)f2bf(acc[c+6]*sc) | ((uint)f2bf(acc[c+7]*sc) << 16);
            *(uint4*)(o + c) = p;
        }
    }
}

// ---------------- GCN aggregation (dinv[src] pre-folded into h16) ----------

__launch_bounds__(256) __global__
void k_gcn(const int* __restrict__ row_off, const int2* __restrict__ csr,
           const float* __restrict__ dinv, const ushort* __restrict__ h16,
           float* __restrict__ out) {
    int lane = threadIdx.x & 63;
    int node = blockIdx.x * 4 + (threadIdx.x >> 6);
    int base = row_off[node], end = row_off[node + 1];
    float dn = dinv[node];
    int grp = lane >> 4, sl = lane & 15;
    float acc[8];
#pragma unroll
    for (int j = 0; j < 8; ++j) acc[j] = 0.f;
    int na = end - 1;
    int i0 = base + grp;
    int2 eA = csr[imin(i0, na)];
    int2 eB = csr[imin(i0 + 4, na)];
    for (int i = i0; i < end; i += 8) {
        int2 eA2 = csr[imin(i + 8,  na)];
        int2 eB2 = csr[imin(i + 12, na)];
        uint4 qA = *(const uint4*)(h16 + (size_t)eA.x * 128 + sl * 8);
        uint4 qB = *(const uint4*)(h16 + (size_t)eB.x * 128 + sl * 8);
        float cA = __int_as_float(eA.y) * dn;       // dinv[s] already in h16
        float cB = (i + 4 < end) ? __int_as_float(eB.y) * dn : 0.f;
        acc[0] = fmaf(cA, __uint_as_float(qA.x << 16),         fmaf(cB, __uint_as_float(qB.x << 16),         acc[0]));
        acc[1] = fmaf(cA, __uint_as_float(qA.x & 0xffff0000u), fmaf(cB, __uint_as_float(qB.x & 0xffff0000u), acc[1]));
        acc[2] = fmaf(cA, __uint_as_float(qA.y << 16),         fmaf(cB, __uint_as_float(qB.y << 16),         acc[2]));
        acc[3] = fmaf(cA, __uint_as_float(qA.y & 0xffff0000u), fmaf(cB, __uint_as_float(qB.y & 0xffff0000u), acc[3]));
        acc[4] = fmaf(cA, __uint_as_float(qA.z << 16),         fmaf(cB, __uint_as_float(qB.z << 16),         acc[4]));
        acc[5] = fmaf(cA, __uint_as_float(qA.z & 0xffff0000u), fmaf(cB, __uint_as_float(qB.z & 0xffff0000u), acc[5]));
        acc[6] = fmaf(cA, __uint_as_float(qA.w << 16),         fmaf(cB, __uint_as_float(qB.w << 16),         acc[6]));
        acc[7] = fmaf(cA, __uint_as_float(qA.w & 0xffff0000u), fmaf(cB, __uint_as_float(qB.w & 0xffff0000u), acc[7]));
        eA = eA2; eB = eB2;
    }
#pragma unroll
    for (int j = 0; j < 8; ++j) {
        acc[j] += __shfl_xor(acc[j], 16);
        acc[j] += __shfl_xor(acc[j], 32);
    }
    if (grp == 0) {
        float* o = out + (size_t)node * 128 + sl * 8;
        *(float4*)(o)     = make_float4(acc[0], acc[1], acc[2], acc[3]);
        *(float4*)(o + 4) = make_float4(acc[4], acc[5], acc[6], acc[7]);
    }
}

// ---------------- launch ----------------

extern "C" void kernel_launch(void* const* d_in, const int* in_sizes, int n_in,
                              void* d_out, int out_size, void* d_ws, size_t ws_size,
                              hipStream_t stream) {
    const float* x    = (const float*)d_in[0];
    const int*   ei   = (const int*)  d_in[1];   // [2,E]: src then dst
    const float* ew   = (const float*)d_in[2];
    const float* Wg   = (const float*)d_in[3];
    const float* atts = (const float*)d_in[4];
    const float* attd = (const float*)d_in[5];
    const float* Wc   = (const float*)d_in[6];
    float* out = (float*)d_out;

    float* a_s   = (float*)d_ws;             // 400000
    float* a_d   = a_s + 400000;             // 400000
    float* dinvp = a_d + 400000;             // 100000
    int* row_off = (int*)(dinvp + 100000);   // 100004
    int* bcnt    = row_off + 100004;         // NB
    int* boff    = bcnt + NB;                // NB + 1
    int* bcsr    = boff + NB + 1;            // NB
    int* bfill   = bcsr + NB;                // NB
    long long* csr = (long long*)(bfill + NB + 1);  // pad -> 8B aligned; 1.7M x 8B
    ushort* xp16 = (ushort*)(csr + 1700000);        // 12.8M bf16
    ushort* h16  = xp16 + 12800000;                 // 12.8M bf16
    long long* binned = (long long*)h16;    // alias: binned dead before h16 written

    const int* srcv = ei;
    const int* dstv = ei + EE;

    hipMemsetAsync(bcnt, 0, NB * sizeof(int), stream);
    k_bcount <<<NTILES, 256, 0, stream>>>(dstv, bcnt);
    k_bprefix<<<1, NB, 0, stream>>>(bcnt, boff, bcsr, bfill);
    k_bin    <<<NTILES, 256, 0, stream>>>(srcv, dstv, ew, bfill, binned);
    k_fine_gemm<<<NB + GEMM_BLKS, 256, 0, stream>>>(
        binned, boff, bcsr, row_off, csr,
        x, Wg, xp16, atts, attd, a_s, a_d);
    k_gat_g2<<<GEMM_BLKS, 512, 0, stream>>>(row_off, (const int2*)csr, a_s, a_d,
                                            xp16, Wc, h16, dinvp);
    k_gcn  <<<NN / 4, 256, 0, stream>>>(row_off, (const int2*)csr, dinvp, h16, out);
}

// Round 5
// 452.321 us; speedup vs baseline: 1.2328x; 1.0091x over previous
//
#include <hip/hip_runtime.h>

#define NN 100000
#define EE 1600000
#define TOT (EE + NN)
#define NEG 0.2f
#define NB 256                      // dst buckets (one fine-block each)
#define CH 391                      // nodes per bucket = ceil(NN/NB)
#define TILE 4096                   // edges per bin block
#define NTILES ((EE + TILE - 1) / TILE)   // 391
#define GEMM_BLKS ((NN + 63) / 64)  // 1563
#define LDA 132                     // LDS row stride (floats): 16B-aligned

typedef unsigned int uint;
typedef unsigned short ushort;

#define BLO(u) __uint_as_float((u) << 16)
#define BHI(u) __uint_as_float((u) & 0xffff0000u)

__device__ inline ushort f2bf(float f) {            // RNE f32 -> bf16
    uint u = __float_as_uint(f);
    return (ushort)((u + 0x7fff + ((u >> 16) & 1)) >> 16);
}

__device__ inline int imin(int a, int b) { return a < b ? a : b; }

// ---------------- bucket count ----------------

__launch_bounds__(256) __global__
void k_bcount(const int* __restrict__ dst, int* __restrict__ bcnt) {
    __shared__ int h[NB];
    int t = threadIdx.x;
    h[t] = 0;
    __syncthreads();
    int base = blockIdx.x * TILE;
#pragma unroll
    for (int r = 0; r < 16; ++r) {
        int e = base + r * 256 + t;
        if (e < EE) atomicAdd(&h[dst[e] / CH], 1);
    }
    __syncthreads();
    if (h[t]) atomicAdd(&bcnt[t], h[t]);
}

// ---------------- bucket prefix (1 block) ----------------

__launch_bounds__(NB) __global__
void k_bprefix(const int* __restrict__ bcnt, int* __restrict__ boff,
               int* __restrict__ bcsr, int* __restrict__ bfill) {
    __shared__ int s1[NB], s2[NB];
    int t = threadIdx.x;
    int c = bcnt[t];
    int nb0 = t * CH;
    int nib = imin(nb0 + CH, NN) - nb0;     // nodes in this bucket
    s1[t] = c; s2[t] = c + nib;
    __syncthreads();
    for (int off = 1; off < NB; off <<= 1) {
        int a = (t >= off) ? s1[t - off] : 0;
        int b = (t >= off) ? s2[t - off] : 0;
        __syncthreads();
        s1[t] += a; s2[t] += b;
        __syncthreads();
    }
    int ex = s1[t] - c;
    boff[t] = ex;
    bfill[t] = ex;
    bcsr[t] = s2[t] - (c + nib);
    if (t == NB - 1) boff[NB] = EE;
}

// ---------------- bin pass: LDS multi-split, coalesced global writes --------

__launch_bounds__(256) __global__
void k_bin(const int* __restrict__ src, const int* __restrict__ dst,
           const float* __restrict__ ew, int* __restrict__ bfill,
           long long* __restrict__ binned) {
    __shared__ long long recs[TILE];   // 32 KB, bucket-ordered staging
    __shared__ ushort    bkt[TILE];    // 8 KB
    __shared__ int hist[NB], eoff[NB], gbase[NB];
    int t = threadIdx.x;
    hist[t] = 0;
    __syncthreads();
    int base = blockIdx.x * TILE;
    int cnt = imin(TILE, EE - base);
    long long rec[16]; int binfo[16];
#pragma unroll
    for (int r = 0; r < 16; ++r) {
        int i = r * 256 + t;
        if (i < cnt) {
            int e = base + i;
            int s = src[e], d = dst[e];
            float w = ew[e];
            int b = d / CH;
            int ldst = d - b * CH;
            int rk = atomicAdd(&hist[b], 1);          // LDS atomic = within-tile rank
            rec[r] = (long long)(uint)(s | (ldst << 17)) |
                     ((long long)__float_as_uint(w) << 32);
            binfo[r] = b | (rk << 8);
        }
    }
    __syncthreads();
    int c = hist[t];
    eoff[t] = c;
    __syncthreads();
    for (int off = 1; off < NB; off <<= 1) {          // inclusive scan
        int a = (t >= off) ? eoff[t - off] : 0;
        __syncthreads();
        eoff[t] += a;
        __syncthreads();
    }
    int ex = eoff[t] - c;                             // own exclusive offset
    gbase[t] = atomicAdd(&bfill[t], c);               // reserve contiguous chunk
    eoff[t] = ex;
    __syncthreads();
#pragma unroll
    for (int r = 0; r < 16; ++r) {                    // stage bucket-ordered in LDS
        int i = r * 256 + t;
        if (i < cnt) {
            int b = binfo[r] & 255, rk = binfo[r] >> 8;
            int slot = eoff[b] + rk;
            recs[slot] = rec[r];
            bkt[slot] = (ushort)b;
        }
    }
    __syncthreads();
#pragma unroll
    for (int r = 0; r < 16; ++r) {                    // coalesced runs (~128B/bucket)
        int i = r * 256 + t;
        if (i < cnt) {
            int b = bkt[i];
            binned[gbase[b] + (i - eoff[b])] = recs[i];
        }
    }
}

// ---------------- gemm1 body (xp = x @ Wg, bf16 out + logit epilogue) -------

__device__ __forceinline__ void gemm1_body(
    int bid, const float* __restrict__ A, const float* __restrict__ W,
    ushort* __restrict__ C16, const float* __restrict__ att_s,
    const float* __restrict__ att_d, float* __restrict__ a_s,
    float* __restrict__ a_d) {
    int lane = threadIdx.x & 63;
    int cg = __builtin_amdgcn_readfirstlane(threadIdx.x >> 6);  // 0..3
    int row = bid * 64 + lane;
    bool valid = row < NN;
    if (!valid) row = NN - 1;
    const float* __restrict__ a = A + (size_t)row * 128;
    const float* __restrict__ w = W + cg * 32;
    float acc[32];
#pragma unroll
    for (int c = 0; c < 32; ++c) acc[c] = 0.f;
    float4 xv = *(const float4*)(a);
    for (int k = 0; k < 128; k += 4) {
        float4 nx = xv;
        if (k < 124) nx = *(const float4*)(a + k + 4);   // 1-ahead prefetch
        float xs[4] = {xv.x, xv.y, xv.z, xv.w};
#pragma unroll
        for (int kk = 0; kk < 4; ++kk) {
            const float* wr = w + (k + kk) * 128;
            float xk = xs[kk];
#pragma unroll
            for (int c = 0; c < 32; ++c) acc[c] = fmaf(xk, wr[c], acc[c]);
        }
        xv = nx;
    }
    if (valid) {
        ushort* o = C16 + (size_t)row * 128 + cg * 32;
#pragma unroll
        for (int c = 0; c < 32; c += 8) {
            uint4 p;
            p.x = (uint)f2bf(acc[c+0]) | ((uint)f2bf(acc[c+1]) << 16);
            p.y = (uint)f2bf(acc[c+2]) | ((uint)f2bf(acc[c+3]) << 16);
            p.z = (uint)f2bf(acc[c+4]) | ((uint)f2bf(acc[c+5]) << 16);
            p.w = (uint)f2bf(acc[c+6]) | ((uint)f2bf(acc[c+7]) << 16);
            *(uint4*)(o + c) = p;
        }
        const float* as = att_s + cg * 32;
        const float* ad = att_d + cg * 32;
        float s0 = 0.f, s1 = 0.f;
#pragma unroll
        for (int c = 0; c < 32; ++c) {
            s0 = fmaf(acc[c], as[c], s0);
            s1 = fmaf(acc[c], ad[c], s1);
        }
        a_s[row * 4 + cg] = s0;
        a_d[row * 4 + cg] = s1;
    }
}

// ---------------- fused: fine scatter (L2-resident per bucket) + gemm1 ------

__launch_bounds__(256) __global__
void k_fine_gemm(const long long* __restrict__ binned, const int* __restrict__ boff,
                 const int* __restrict__ bcsr, int* __restrict__ row_off,
                 long long* __restrict__ csr,
                 const float* __restrict__ A, const float* __restrict__ W,
                 ushort* __restrict__ C16, const float* __restrict__ att_s,
                 const float* __restrict__ att_d, float* __restrict__ a_s,
                 float* __restrict__ a_d) {
    if (blockIdx.x >= NB) {
        gemm1_body(blockIdx.x - NB, A, W, C16, att_s, att_d, a_s, a_d);
        return;
    }
    __shared__ int hist[CH];
    __shared__ int excl[CH];
    __shared__ int sc[512];
    int t = threadIdx.x;
    int b = blockIdx.x;
    int e0 = boff[b], e1 = boff[b + 1];
    int nb0 = b * CH;
    int nnode = imin(CH, NN - nb0);
    const int2* __restrict__ bn = (const int2*)binned;
    hist[t] = 0;
    if (t + 256 < CH) hist[t + 256] = 0;
    __syncthreads();
    for (int i = e0 + t; i < e1; i += 256)            // pass 1: per-node counts
        atomicAdd(&hist[bn[i].x >> 17], 1);
    __syncthreads();
    int v0 = (t < nnode) ? hist[t] + 1 : 0;           // +1 self-loop
    int v1 = (t + 256 < nnode) ? hist[t + 256] + 1 : 0;
    sc[t] = v0; sc[t + 256] = v1;
    __syncthreads();
    for (int off = 1; off < 512; off <<= 1) {         // Hillis-Steele, 2 elems/thread
        int a0 = (t >= off) ? sc[t - off] : 0;
        int a1 = (t + 256 >= off) ? sc[t + 256 - off] : 0;
        __syncthreads();
        sc[t] += a0; sc[t + 256] += a1;
        __syncthreads();
    }
    int csr0 = bcsr[b];
    if (t < nnode) {
        excl[t] = csr0 + sc[t] - v0;
        row_off[nb0 + t] = excl[t];
    }
    if (t + 256 < nnode) {
        excl[t + 256] = csr0 + sc[t + 256] - v1;
        row_off[nb0 + t + 256] = excl[t + 256];
    }
    if (b == 0 && t == 0) row_off[NN] = TOT;
    hist[t] = 0;                                      // reset -> rank counters
    if (t + 256 < CH) hist[t + 256] = 0;
    __syncthreads();
    for (int i = e0 + t; i < e1; i += 256) {          // pass 2: L2-window scatter
        int2 r = bn[i];
        int ld = r.x >> 17;
        int rk = atomicAdd(&hist[ld], 1);
        long long rec = (long long)(uint)(r.x & 0x1FFFF) |
                        ((long long)(uint)r.y << 32);
        csr[excl[ld] + rk] = rec;
    }
    __syncthreads();
    for (int i = t; i < nnode; i += 256) {            // self-loops at row end, w = 1
        int n = nb0 + i;
        csr[excl[i] + hist[i]] = (long long)(uint)n | (0x3F800000LL << 32);
    }
}

// ---------------- fused GAT aggregation + GEMM2 (512-thread blocks) ----------
// 4-deep MLP in the gather loop: 4 csr prefetches + 4 row-gathers + 4 a_s
// reads in flight per 16-lane group before any consumption. Avg degree ~17
// -> ~4.25 edges/group -> one iteration typically covers a whole row.

__launch_bounds__(512) __global__
void k_gat_g2(const int* __restrict__ row_off, const int2* __restrict__ csr,
              const float* __restrict__ a_s, const float* __restrict__ a_d,
              const ushort* __restrict__ xp16, const float* __restrict__ W,
              ushort* __restrict__ h16, float* __restrict__ dinv) {
    __shared__ float As[64 * LDA];
    __shared__ float sdinv[64];
    int lane = threadIdx.x & 63;
    int wv = threadIdx.x >> 6;              // 0..7
    int grp = lane >> 4, sl = lane & 15, h2 = sl >> 2;
    int nbase = blockIdx.x * 64;

    for (int rnd = 0; rnd < 8; ++rnd) {
        int r = (rnd << 3) | wv;            // row in block, 0..63
        int node = nbase + r;
        if (node < NN) {
            int base = row_off[node], end = row_off[node + 1];
            float adh = a_d[node * 4 + h2];
            float acc[8];
#pragma unroll
            for (int j = 0; j < 8; ++j) acc[j] = 0.f;
            float den = 0.f, wsum = 0.f;
            int na = end - 1;
            int i0 = base + grp;
            int2 e0v = csr[imin(i0,      na)];
            int2 e1v = csr[imin(i0 + 4,  na)];
            int2 e2v = csr[imin(i0 + 8,  na)];
            int2 e3v = csr[imin(i0 + 12, na)];
            for (int i = i0; i < end; i += 16) {
                int2 p0 = csr[imin(i + 16, na)];        // prefetch next trip
                int2 p1 = csr[imin(i + 20, na)];
                int2 p2 = csr[imin(i + 24, na)];
                int2 p3 = csr[imin(i + 28, na)];
                uint4 q0 = *(const uint4*)(xp16 + (size_t)e0v.x * 128 + sl * 8);
                uint4 q1 = *(const uint4*)(xp16 + (size_t)e1v.x * 128 + sl * 8);
                uint4 q2 = *(const uint4*)(xp16 + (size_t)e2v.x * 128 + sl * 8);
                uint4 q3 = *(const uint4*)(xp16 + (size_t)e3v.x * 128 + sl * 8);
                float al0 = a_s[e0v.x * 4 + h2] + adh;
                float al1 = a_s[e1v.x * 4 + h2] + adh;
                float al2 = a_s[e2v.x * 4 + h2] + adh;
                float al3 = a_s[e3v.x * 4 + h2] + adh;
                al0 = al0 > 0.f ? al0 : NEG * al0;
                al1 = al1 > 0.f ? al1 : NEG * al1;
                al2 = al2 > 0.f ? al2 : NEG * al2;
                al3 = al3 > 0.f ? al3 : NEG * al3;
                float aw0 = __expf(al0);                     // i < end always
                float aw1 = (i + 4  < end) ? __expf(al1) : 0.f;
                float aw2 = (i + 8  < end) ? __expf(al2) : 0.f;
                float aw3 = (i + 12 < end) ? __expf(al3) : 0.f;
                float w0 = __int_as_float(e0v.y);
                float w1 = (i + 4  < end) ? __int_as_float(e1v.y) : 0.f;
                float w2 = (i + 8  < end) ? __int_as_float(e2v.y) : 0.f;
                float w3 = (i + 12 < end) ? __int_as_float(e3v.y) : 0.f;
                den  += (aw0 + aw1) + (aw2 + aw3);
                wsum += (w0 + w1) + (w2 + w3);
                acc[0] = fmaf(aw0, BLO(q0.x), fmaf(aw1, BLO(q1.x), fmaf(aw2, BLO(q2.x), fmaf(aw3, BLO(q3.x), acc[0]))));
                acc[1] = fmaf(aw0, BHI(q0.x), fmaf(aw1, BHI(q1.x), fmaf(aw2, BHI(q2.x), fmaf(aw3, BHI(q3.x), acc[1]))));
                acc[2] = fmaf(aw0, BLO(q0.y), fmaf(aw1, BLO(q1.y), fmaf(aw2, BLO(q2.y), fmaf(aw3, BLO(q3.y), acc[2]))));
                acc[3] = fmaf(aw0, BHI(q0.y), fmaf(aw1, BHI(q1.y), fmaf(aw2, BHI(q2.y), fmaf(aw3, BHI(q3.y), acc[3]))));
                acc[4] = fmaf(aw0, BLO(q0.z), fmaf(aw1, BLO(q1.z), fmaf(aw2, BLO(q2.z), fmaf(aw3, BLO(q3.z), acc[4]))));
                acc[5] = fmaf(aw0, BHI(q0.z), fmaf(aw1, BHI(q1.z), fmaf(aw2, BHI(q2.z), fmaf(aw3, BHI(q3.z), acc[5]))));
                acc[6] = fmaf(aw0, BLO(q0.w), fmaf(aw1, BLO(q1.w), fmaf(aw2, BLO(q2.w), fmaf(aw3, BLO(q3.w), acc[6]))));
                acc[7] = fmaf(aw0, BHI(q0.w), fmaf(aw1, BHI(q1.w), fmaf(aw2, BHI(q2.w), fmaf(aw3, BHI(q3.w), acc[7]))));
                e0v = p0; e1v = p1; e2v = p2; e3v = p3;
            }
#pragma unroll
            for (int j = 0; j < 8; ++j) {
                acc[j] += __shfl_xor(acc[j], 16);
                acc[j] += __shfl_xor(acc[j], 32);
            }
            den  += __shfl_xor(den, 16);   den  += __shfl_xor(den, 32);
            wsum += __shfl_xor(wsum, 16);  wsum += __shfl_xor(wsum, 32);
            if (grp == 0) {
                float il = 1.f / den;
                float* o = &As[r * LDA + sl * 8];
                *(float4*)(o)     = make_float4(acc[0]*il, acc[1]*il, acc[2]*il, acc[3]*il);
                *(float4*)(o + 4) = make_float4(acc[4]*il, acc[5]*il, acc[6]*il, acc[7]*il);
                if (sl == 0) {
                    float dv = rsqrtf(wsum);
                    sdinv[r] = dv;
                    dinv[node] = dv;        // k_gcn needs the dst-side factor
                }
            }
        } else if (grp == 0) {              // tail block: zero-fill invalid rows
            float* o = &As[r * LDA + sl * 8];
            *(float4*)(o)     = make_float4(0.f, 0.f, 0.f, 0.f);
            *(float4*)(o + 4) = make_float4(0.f, 0.f, 0.f, 0.f);
            if (sl == 0) sdinv[r] = 0.f;
        }
    }
    __syncthreads();

    // ---- phase 2: gemm2 body, A from LDS (row = lane, cg = wave, 16 cols) ----
    int cg = __builtin_amdgcn_readfirstlane(wv);    // 0..7
    int row = nbase + lane;
    bool valid = row < NN;
    const float* __restrict__ w = W + cg * 16;
    const float* __restrict__ a = &As[lane * LDA];
    float acc[16];
#pragma unroll
    for (int c = 0; c < 16; ++c) acc[c] = 0.f;
    for (int k = 0; k < 128; k += 4) {
        float4 xv = *(const float4*)(a + k);
        float xs[4] = {xv.x, xv.y, xv.z, xv.w};
#pragma unroll
        for (int kk = 0; kk < 4; ++kk) {
            const float* wr = w + (k + kk) * 128;
            float xk = xs[kk];
#pragma unroll
            for (int c = 0; c < 16; ++c) acc[c] = fmaf(xk, wr[c], acc[c]);
        }
    }
    if (valid) {
        float sc = sdinv[lane];                 // fold dinv[src] into the row
        ushort* o = h16 + (size_t)row * 128 + cg * 16;
#pragma unroll
        for (int c = 0; c < 16; c += 8) {
            uint4 p;
            p.x = (uint)f2bf(acc[c+0]*sc) | ((uint)f2bf(acc[c+1]*sc) << 16);
            p.y = (uint)f2bf(acc[c+2]*sc) | ((uint)f2bf(acc[c+3]*sc) << 16);
            p.z = (uint)f2bf(acc[c+4]*sc) | ((uint)f2bf(acc[c+5]*sc) << 16);
            p.w = (uint)f2bf(acc[c+6]*sc) | ((uint)f2bf(acc[c+7]*sc) << 16);
            *(uint4*)(o + c) = p;
        }
    }
}

// ---------------- GCN aggregation (dinv[src] pre-folded into h16) ----------
// Same 4-deep MLP as k_gat_g2 phase 1.

__launch_bounds__(256) __global__
void k_gcn(const int* __restrict__ row_off, const int2* __restrict__ csr,
           const float* __restrict__ dinv, const ushort* __restrict__ h16,
           float* __restrict__ out) {
    int lane = threadIdx.x & 63;
    int node = blockIdx.x * 4 + (threadIdx.x >> 6);
    int base = row_off[node], end = row_off[node + 1];
    float dn = dinv[node];
    int grp = lane >> 4, sl = lane & 15;
    float acc[8];
#pragma unroll
    for (int j = 0; j < 8; ++j) acc[j] = 0.f;
    int na = end - 1;
    int i0 = base + grp;
    int2 e0v = csr[imin(i0,      na)];
    int2 e1v = csr[imin(i0 + 4,  na)];
    int2 e2v = csr[imin(i0 + 8,  na)];
    int2 e3v = csr[imin(i0 + 12, na)];
    for (int i = i0; i < end; i += 16) {
        int2 p0 = csr[imin(i + 16, na)];
        int2 p1 = csr[imin(i + 20, na)];
        int2 p2 = csr[imin(i + 24, na)];
        int2 p3 = csr[imin(i + 28, na)];
        uint4 q0 = *(const uint4*)(h16 + (size_t)e0v.x * 128 + sl * 8);
        uint4 q1 = *(const uint4*)(h16 + (size_t)e1v.x * 128 + sl * 8);
        uint4 q2 = *(const uint4*)(h16 + (size_t)e2v.x * 128 + sl * 8);
        uint4 q3 = *(const uint4*)(h16 + (size_t)e3v.x * 128 + sl * 8);
        float c0 = __int_as_float(e0v.y) * dn;          // dinv[s] already in h16
        float c1 = (i + 4  < end) ? __int_as_float(e1v.y) * dn : 0.f;
        float c2 = (i + 8  < end) ? __int_as_float(e2v.y) * dn : 0.f;
        float c3 = (i + 12 < end) ? __int_as_float(e3v.y) * dn : 0.f;
        acc[0] = fmaf(c0, BLO(q0.x), fmaf(c1, BLO(q1.x), fmaf(c2, BLO(q2.x), fmaf(c3, BLO(q3.x), acc[0]))));
        acc[1] = fmaf(c0, BHI(q0.x), fmaf(c1, BHI(q1.x), fmaf(c2, BHI(q2.x), fmaf(c3, BHI(q3.x), acc[1]))));
        acc[2] = fmaf(c0, BLO(q0.y), fmaf(c1, BLO(q1.y), fmaf(c2, BLO(q2.y), fmaf(c3, BLO(q3.y), acc[2]))));
        acc[3] = fmaf(c0, BHI(q0.y), fmaf(c1, BHI(q1.y), fmaf(c2, BHI(q2.y), fmaf(c3, BHI(q3.y), acc[3]))));
        acc[4] = fmaf(c0, BLO(q0.z), fmaf(c1, BLO(q1.z), fmaf(c2, BLO(q2.z), fmaf(c3, BLO(q3.z), acc[4]))));
        acc[5] = fmaf(c0, BHI(q0.z), fmaf(c1, BHI(q1.z), fmaf(c2, BHI(q2.z), fmaf(c3, BHI(q3.z), acc[5]))));
        acc[6] = fmaf(c0, BLO(q0.w), fmaf(c1, BLO(q1.w), fmaf(c2, BLO(q2.w), fmaf(c3, BLO(q3.w), acc[6]))));
        acc[7] = fmaf(c0, BHI(q0.w), fmaf(c1, BHI(q1.w), fmaf(c2, BHI(q2.w), fmaf(c3, BHI(q3.w), acc[7]))));
        e0v = p0; e1v = p1; e2v = p2; e3v = p3;
    }
#pragma unroll
    for (int j = 0; j < 8; ++j) {
        acc[j] += __shfl_xor(acc[j], 16);
        acc[j] += __shfl_xor(acc[j], 32);
    }
    if (grp == 0) {
        float* o = out + (size_t)node * 128 + sl * 8;
        *(float4*)(o)     = make_float4(acc[0], acc[1], acc[2], acc[3]);
        *(float4*)(o + 4) = make_float4(acc[4], acc[5], acc[6], acc[7]);
    }
}

// ---------------- launch ----------------

extern "C" void kernel_launch(void* const* d_in, const int* in_sizes, int n_in,
                              void* d_out, int out_size, void* d_ws, size_t ws_size,
                              hipStream_t stream) {
    const float* x    = (const float*)d_in[0];
    const int*   ei   = (const int*)  d_in[1];   // [2,E]: src then dst
    const float* ew   = (const float*)d_in[2];
    const float* Wg   = (const float*)d_in[3];
    const float* atts = (const float*)d_in[4];
    const float* attd = (const float*)d_in[5];
    const float* Wc   = (const float*)d_in[6];
    float* out = (float*)d_out;

    float* a_s   = (float*)d_ws;             // 400000
    float* a_d   = a_s + 400000;             // 400000
    float* dinvp = a_d + 400000;             // 100000
    int* row_off = (int*)(dinvp + 100000);   // 100004
    int* bcnt    = row_off + 100004;         // NB
    int* boff    = bcnt + NB;                // NB + 1
    int* bcsr    = boff + NB + 1;            // NB
    int* bfill   = bcsr + NB;                // NB
    long long* csr = (long long*)(bfill + NB + 1);  // pad -> 8B aligned; 1.7M x 8B
    ushort* xp16 = (ushort*)(csr + 1700000);        // 12.8M bf16
    ushort* h16  = xp16 + 12800000;                 // 12.8M bf16
    long long* binned = (long long*)h16;    // alias: binned dead before h16 written

    const int* srcv = ei;
    const int* dstv = ei + EE;

    hipMemsetAsync(bcnt, 0, NB * sizeof(int), stream);
    k_bcount <<<NTILES, 256, 0, stream>>>(dstv, bcnt);
    k_bprefix<<<1, NB, 0, stream>>>(bcnt, boff, bcsr, bfill);
    k_bin    <<<NTILES, 256, 0, stream>>>(srcv, dstv, ew, bfill, binned);
    k_fine_gemm<<<NB + GEMM_BLKS, 256, 0, stream>>>(
        binned, boff, bcsr, row_off, csr,
        x, Wg, xp16, atts, attd, a_s, a_d);
    k_gat_g2<<<GEMM_BLKS, 512, 0, stream>>>(row_off, (const int2*)csr, a_s, a_d,
                                            xp16, Wc, h16, dinvp);
    k_gcn  <<<NN / 4, 256, 0, stream>>>(row_off, (const int2*)csr, dinvp, h16, out);
}